// Round 1
// baseline (361.515 us; speedup 1.0000x reference)
//
#include <hip/hip_runtime.h>

// Orient_Conv: 3x3 orientation-gated conv over 4 orientations + per-pixel
// max/argmax. B=4, CIN=COUT=32, H=W=128, pad=1, stride=1.
//
// Identity used: gate_o = relu(cos(wr + o*pi/2 - theta)) with r0=cos(theta),
// r1=sin(theta):  u = C*r0 + S*r1 (= cos(wr-theta)), v = C*r1 - S*r0
//   o=0: relu(u), o=1: relu(v), o=2: relu(-u), o=3: relu(-v)
// Weight rotation (rot90 applied o times), at tap (i,j):
//   w0 = w[i][j], w1 = w[2-j][i], w2 = w[2-i][2-j], w3 = w[j][2-i]
//
// Block = one (b, h) row, all 32 oc. 256 threads = 32 px-lanes x 8 oc-groups.
// Thread: 4 pixels (w = px0 + {0,32,64,96}) x 4 oc x 4 orients = 64 accs.

#define B_    4
#define CIN_  32
#define COUT_ 32
#define H_    128
#define W_    128
#define OUTSZ_ (B_ * COUT_ * H_ * W_)   // 2097152 per output tensor

__global__ __launch_bounds__(256, 2)
void orient_conv_kernel(const float* __restrict__ f,
                        const float* __restrict__ r0,
                        const float* __restrict__ r1,
                        const float* __restrict__ w,
                        const float* __restrict__ wr,
                        float* __restrict__ out)
{
    __shared__ float sIn[3][3][132];   // {f,r0,r1} x 3 rows x cols(-1..128)
    __shared__ float sW[9][32][8];     // tap x oc x {C,S,w0,w1,w2,w3,pad,pad}

    const int tid = threadIdx.x;
    const int bid = blockIdx.x;
    const int b   = bid >> 7;          // 0..3
    const int h   = bid & 127;         // 0..127
    const int px0 = tid & 31;          // pixel lane
    const int ocg = tid >> 5;          // 0..7
    const int oc0 = ocg << 2;          // 4 oc per thread

    float acc[4][4][4];
#pragma unroll
    for (int k = 0; k < 4; ++k)
#pragma unroll
        for (int q = 0; q < 4; ++q)
#pragma unroll
            for (int o = 0; o < 4; ++o) acc[k][q][o] = 0.0f;

    for (int c = 0; c < CIN_; ++c) {
        // ---- stage input halo rows (h-1..h+1, w-1..128) for this c ----
        for (int idx = tid; idx < 3 * 130; idx += 256) {
            int row = idx / 130;             // 0..2
            int col = idx - row * 130;       // 0..129
            int gh = h + row - 1;
            int gw = col - 1;
            bool ok = ((unsigned)gh < (unsigned)H_) & ((unsigned)gw < (unsigned)W_);
            int off = ((b * CIN_ + c) * H_ + gh) * W_ + gw;
            sIn[0][row][col] = ok ? f[off]  : 0.0f;
            sIn[1][row][col] = ok ? r0[off] : 0.0f;
            sIn[2][row][col] = ok ? r1[off] : 0.0f;
        }
        // ---- stage weights for this c: 9 taps x 32 oc ----
        for (int idx = tid; idx < 288; idx += 256) {
            int oc  = idx & 31;
            int tap = idx >> 5;              // 0..8
            int i = tap / 3;
            int j = tap - i * 3;
            const int base = (oc * CIN_ + c) * 9;
            float wv0 = w[base + i * 3 + j];
            float wv1 = w[base + (2 - j) * 3 + i];
            float wv2 = w[base + (2 - i) * 3 + (2 - j)];
            float wv3 = w[base + j * 3 + (2 - i)];
            float wrv = wr[base + i * 3 + j];
            float S, C;
            sincosf(wrv, &S, &C);
            float4* dst = reinterpret_cast<float4*>(&sW[tap][oc][0]);
            dst[0] = make_float4(C, S, wv0, wv1);
            dst[1] = make_float4(wv2, wv3, 0.0f, 0.0f);
        }
        __syncthreads();

        // ---- compute: 9 taps x 4 oc x 4 px x 4 orientations ----
        for (int tap = 0; tap < 9; ++tap) {
            int i = tap / 3;
            int j = tap - i * 3;
            float fv[4], r0v[4], r1v[4];
#pragma unroll
            for (int k = 0; k < 4; ++k) {
                int col = px0 + (k << 5) + j;    // 0..129
                fv[k]  = sIn[0][i][col];
                r0v[k] = sIn[1][i][col];
                r1v[k] = sIn[2][i][col];
            }
#pragma unroll
            for (int q = 0; q < 4; ++q) {
                const float4 wA = *reinterpret_cast<const float4*>(&sW[tap][oc0 + q][0]);
                const float4 wB = *reinterpret_cast<const float4*>(&sW[tap][oc0 + q][4]);
                const float C  = wA.x, S  = wA.y;
                const float w0 = wA.z, w1 = wA.w;
                const float w2 = wB.x, w3 = wB.y;
#pragma unroll
                for (int k = 0; k < 4; ++k) {
                    float u = fmaf(C, r0v[k], S * r1v[k]);    // cos(wr - theta)
                    float v = fmaf(C, r1v[k], -S * r0v[k]);   // -sin(wr - theta)
                    acc[k][q][0] = fmaf(fv[k] * w0, fmaxf(u, 0.0f),  acc[k][q][0]);
                    acc[k][q][1] = fmaf(fv[k] * w1, fmaxf(v, 0.0f),  acc[k][q][1]);
                    acc[k][q][2] = fmaf(fv[k] * w2, fmaxf(-u, 0.0f), acc[k][q][2]);
                    acc[k][q][3] = fmaf(fv[k] * w3, fmaxf(-v, 0.0f), acc[k][q][3]);
                }
            }
        }
        __syncthreads();
    }

    // ---- epilogue: max/argmax over orientations (first-max tie-break) ----
    // cos/sin of float32 orient values (match jnp.cos/sin of f32 k*pi/2)
    const float cosv[4] = {1.0f, -4.37113883e-08f, -1.0f, 1.19248806e-08f};
    const float sinv[4] = {0.0f, 1.0f, -8.74227766e-08f, -1.0f};
#pragma unroll
    for (int q = 0; q < 4; ++q) {
        int oc = oc0 + q;
#pragma unroll
        for (int k = 0; k < 4; ++k) {
            int wcol = px0 + (k << 5);
            float a0 = acc[k][q][0], a1 = acc[k][q][1];
            float a2 = acc[k][q][2], a3 = acc[k][q][3];
            float best = a0; int bi = 0;
            if (a1 > best) { best = a1; bi = 1; }
            if (a2 > best) { best = a2; bi = 2; }
            if (a3 > best) { best = a3; bi = 3; }
            size_t o = ((size_t)(b * COUT_ + oc) * H_ + h) * W_ + wcol;
            out[o]              = best;
            out[o + OUTSZ_]     = cosv[bi];
            out[o + 2 * OUTSZ_] = sinv[bi];
        }
    }
}

extern "C" void kernel_launch(void* const* d_in, const int* in_sizes, int n_in,
                              void* d_out, int out_size, void* d_ws, size_t ws_size,
                              hipStream_t stream)
{
    const float* f  = (const float*)d_in[0];
    const float* r0 = (const float*)d_in[1];
    const float* r1 = (const float*)d_in[2];
    const float* w  = (const float*)d_in[3];
    const float* wr = (const float*)d_in[4];
    float* out = (float*)d_out;

    dim3 grid(B_ * H_);   // 512 blocks: one per (b, h)
    dim3 block(256);
    orient_conv_kernel<<<grid, block, 0, stream>>>(f, r0, r1, w, wr, out);
}

// Round 2
// 329.721 us; speedup vs baseline: 1.0964x; 1.0964x over previous
//
#include <hip/hip_runtime.h>

// Orient_Conv: 3x3 orientation-gated conv, 4 orientations + per-pixel argmax.
// B=4, CIN=COUT=32, H=W=128, pad=1.
//
// Gate identity (C=cos(wr), S=sin(wr), r0=cos(th), r1=sin(th)):
//   u = C*r0+S*r1 = cos(wr-th), v = C*r1-S*r0
//   gates: o0=relu(u), o1=relu(v), o2=relu(-u)=relu(u)-u, o3=relu(v)-v
// Weight rotation at tap (i,j): w0=w[i][j], w1=w[2-j][i], w2=w[2-i][2-j],
//   w3=w[j][2-i].
//
// v2f packed-fp32 (v_pk_fma_f32/v_pk_mul_f32): each thread's 2 pixels ride
// in one packed pair. Weights stored duplicated in LDS ({C,C},{S,S},...) so
// packed operands load directly via ds_read_b128 (no broadcast movs).
//
// Grid: 1024 blocks = (b, h, W-half) -> 4 blocks/CU for occupancy.
// Block: 256 thr = 32 px-lanes x 8 oc-groups; thread: 2 px x 4 oc x 4 orient.

typedef float v2f __attribute__((ext_vector_type(2)));

#define B_    4
#define CIN_  32
#define COUT_ 32
#define H_    128
#define W_    128
#define OUTSZ_ (B_ * COUT_ * H_ * W_)

__global__ __launch_bounds__(256, 4)
void orient_conv_kernel(const float* __restrict__ f,
                        const float* __restrict__ r0,
                        const float* __restrict__ r1,
                        const float* __restrict__ w,
                        const float* __restrict__ wr,
                        float* __restrict__ out)
{
    __shared__ float sIn[3][3][68];    // {f,r0,r1} x 3 rows x cols(-1..64)
    __shared__ float sW[9][32][12];    // tap x oc x {C,C,S,S,w0,w0,w1,w1,w2,w2,w3,w3}

    const int tid   = threadIdx.x;
    const int bid   = blockIdx.x;          // 0..1023
    const int b     = bid >> 8;            // 0..3
    const int rem   = bid & 255;
    const int h     = rem >> 1;            // 0..127
    const int wbase = (rem & 1) << 6;      // 0 or 64
    const int px0   = tid & 31;            // pixel lane within half-row
    const int oc0   = (tid >> 5) << 2;     // 4 oc per thread

    v2f acc[4][4];                         // [q][orient], lanes = px {0,+32}
#pragma unroll
    for (int q = 0; q < 4; ++q)
#pragma unroll
        for (int o = 0; o < 4; ++o) acc[q][o] = (v2f)(0.0f);

    for (int c = 0; c < CIN_; ++c) {
        // ---- stage input halo (3 rows x 66 cols) for this c ----
        if (tid < 198) {
            int row = tid / 66;
            int col = tid - row * 66;      // 0..65  -> gw = wbase+col-1
            int gh = h + row - 1;
            int gw = wbase + col - 1;
            bool ok = ((unsigned)gh < (unsigned)H_) & ((unsigned)gw < (unsigned)W_);
            int off = ((b * CIN_ + c) * H_ + gh) * W_ + gw;
            sIn[0][row][col] = ok ? f[off]  : 0.0f;
            sIn[1][row][col] = ok ? r0[off] : 0.0f;
            sIn[2][row][col] = ok ? r1[off] : 0.0f;
        }
        // ---- stage weights (9 taps x 32 oc), duplicated for packed math ----
        for (int idx = tid; idx < 288; idx += 256) {
            int oc  = idx & 31;
            int tap = idx >> 5;
            int i = tap / 3;
            int j = tap - i * 3;
            const int base = (oc * CIN_ + c) * 9;
            float wv0 = w[base + i * 3 + j];
            float wv1 = w[base + (2 - j) * 3 + i];
            float wv2 = w[base + (2 - i) * 3 + (2 - j)];
            float wv3 = w[base + j * 3 + (2 - i)];
            float S, C;
            sincosf(wr[base + i * 3 + j], &S, &C);
            float4* dst = reinterpret_cast<float4*>(&sW[tap][oc][0]);
            dst[0] = make_float4(C, C, S, S);
            dst[1] = make_float4(wv0, wv0, wv1, wv1);
            dst[2] = make_float4(wv2, wv2, wv3, wv3);
        }
        __syncthreads();

        // ---- compute ----
#pragma unroll
        for (int tap = 0; tap < 9; ++tap) {
            const int i = tap / 3;
            const int j = tap - i * 3;
            const int colb = px0 + j;
            v2f fv, r0v, r1v;
            fv[0]  = sIn[0][i][colb]; fv[1]  = sIn[0][i][colb + 32];
            r0v[0] = sIn[1][i][colb]; r0v[1] = sIn[1][i][colb + 32];
            r1v[0] = sIn[2][i][colb]; r1v[1] = sIn[2][i][colb + 32];
#pragma unroll
            for (int q = 0; q < 4; ++q) {
                const float4 wcs = *reinterpret_cast<const float4*>(&sW[tap][oc0 + q][0]);
                const float4 w01 = *reinterpret_cast<const float4*>(&sW[tap][oc0 + q][4]);
                const float4 w23 = *reinterpret_cast<const float4*>(&sW[tap][oc0 + q][8]);
                v2f Cv; Cv[0] = wcs.x; Cv[1] = wcs.y;
                v2f Sv; Sv[0] = wcs.z; Sv[1] = wcs.w;
                v2f w0v; w0v[0] = w01.x; w0v[1] = w01.y;
                v2f w1v; w1v[0] = w01.z; w1v[1] = w01.w;
                v2f w2v; w2v[0] = w23.x; w2v[1] = w23.y;
                v2f w3v; w3v[0] = w23.z; w3v[1] = w23.w;

                v2f u  = __builtin_elementwise_fma(Cv, r0v, Sv * r1v);
                v2f vv = __builtin_elementwise_fma(Cv, r1v, -Sv * r0v);
                v2f g0 = __builtin_elementwise_max(u,  (v2f)(0.0f));
                v2f g1 = __builtin_elementwise_max(vv, (v2f)(0.0f));
                v2f g2 = g0 - u;    // relu(-u), exact
                v2f g3 = g1 - vv;   // relu(-v), exact
                v2f t0 = fv * g0, t1 = fv * g1, t2 = fv * g2, t3 = fv * g3;
                acc[q][0] = __builtin_elementwise_fma(t0, w0v, acc[q][0]);
                acc[q][1] = __builtin_elementwise_fma(t1, w1v, acc[q][1]);
                acc[q][2] = __builtin_elementwise_fma(t2, w2v, acc[q][2]);
                acc[q][3] = __builtin_elementwise_fma(t3, w3v, acc[q][3]);
            }
        }
        __syncthreads();
    }

    // ---- epilogue: max/argmax over orientations (first-max tie-break) ----
    const float cosv[4] = {1.0f, -4.37113883e-08f, -1.0f, 1.19248806e-08f};
    const float sinv[4] = {0.0f, 1.0f, -8.74227766e-08f, -1.0f};
#pragma unroll
    for (int q = 0; q < 4; ++q) {
        int oc = oc0 + q;
#pragma unroll
        for (int k = 0; k < 2; ++k) {
            int wcol = wbase + px0 + (k << 5);
            float a0 = acc[q][0][k], a1 = acc[q][1][k];
            float a2 = acc[q][2][k], a3 = acc[q][3][k];
            float best = a0; int bi = 0;
            if (a1 > best) { best = a1; bi = 1; }
            if (a2 > best) { best = a2; bi = 2; }
            if (a3 > best) { best = a3; bi = 3; }
            size_t o = ((size_t)(b * COUT_ + oc) * H_ + h) * W_ + wcol;
            out[o]              = best;
            out[o + OUTSZ_]     = cosv[bi];
            out[o + 2 * OUTSZ_] = sinv[bi];
        }
    }
}

extern "C" void kernel_launch(void* const* d_in, const int* in_sizes, int n_in,
                              void* d_out, int out_size, void* d_ws, size_t ws_size,
                              hipStream_t stream)
{
    const float* f  = (const float*)d_in[0];
    const float* r0 = (const float*)d_in[1];
    const float* r1 = (const float*)d_in[2];
    const float* w  = (const float*)d_in[3];
    const float* wr = (const float*)d_in[4];
    float* out = (float*)d_out;

    dim3 grid(B_ * H_ * 2);   // 1024 blocks: (b, h, W-half)
    dim3 block(256);
    orient_conv_kernel<<<grid, block, 0, stream>>>(f, r0, r1, w, wr, out);
}

// Round 3
// 320.163 us; speedup vs baseline: 1.1292x; 1.0299x over previous
//
#include <hip/hip_runtime.h>

// Orient_Conv: 3x3 orientation-gated conv, 4 orientations + per-pixel argmax.
// B=4, CIN=COUT=32, H=W=128, pad=1.
//
// Gate identity (C=cos(wr), S=sin(wr), r0=cos(th), r1=sin(th)):
//   u = C*r0+S*r1, v = C*r1-S*r0
//   gates: o0=relu(u), o1=relu(v), o2=relu(-u)=relu(u)-u, o3=relu(v)-v
// Weight rotation at tap (i,j): w0=w[i][j], w1=w[2-j][i], w2=w[2-i][2-j],
//   w3=w[j][2-i].
//
// R2 structure: weights precomputed into d_ws as {C,S,w0..w3} x {ocA,ocB}
// pairs, loaded with wave-uniform addresses (readfirstlane) -> s_load into
// SGPRs -> zero LDS traffic for weights (R1 was LDS-read-pipe bound).
// Wave = 64 pixels (half row); oc-group (8 oc) is wave-uniform. Packed
// v2f math pairs two oc per VOP3P instruction.

typedef float v2f __attribute__((ext_vector_type(2)));

#define B_    4
#define CIN_  32
#define COUT_ 32
#define H_    128
#define W_    128
#define OUTSZ_ (B_ * COUT_ * H_ * W_)

// tab layout: [c][ocg(4)][tap(9)][pair(4)][12]
//   12 = {C_a,C_b, S_a,S_b, w0_a,w0_b, w1_a,w1_b, w2_a,w2_b, w3_a,w3_b}
// oc = ocg*8 + pair*2 + {a:0, b:1}
#define TAB_FLOATS (CIN_ * 4 * 9 * 4 * 12)   // 55296 floats = 221184 B

__global__ __launch_bounds__(256)
void build_wtab(const float* __restrict__ w, const float* __restrict__ wr,
                float* __restrict__ tab)
{
    int idx = blockIdx.x * 256 + threadIdx.x;     // ((t2*9+tap)*4+pair)*2+k
    if (idx >= CIN_ * 4 * 9 * 4 * 2) return;      // 9216
    int k    = idx & 1;
    int r    = idx >> 1;
    int pair = r & 3;
    int r2   = r >> 2;
    int tap  = r2 % 9;
    int t2   = r2 / 9;                            // c*4 + ocg
    int ocg  = t2 & 3;
    int c    = t2 >> 2;
    int oc   = ocg * 8 + pair * 2 + k;
    int i = tap / 3, j = tap - i * 3;
    int base = (oc * CIN_ + c) * 9;
    float w0 = w[base + i * 3 + j];
    float w1 = w[base + (2 - j) * 3 + i];
    float w2 = w[base + (2 - i) * 3 + (2 - j)];
    float w3 = w[base + j * 3 + (2 - i)];
    float S, C;
    sincosf(wr[base + i * 3 + j], &S, &C);
    float* dst = tab + ((size_t)t2 * 9 + tap) * 48 + pair * 12;
    dst[0 + k]  = C;  dst[2 + k]  = S;
    dst[4 + k]  = w0; dst[6 + k]  = w1;
    dst[8 + k]  = w2; dst[10 + k] = w3;
}

__global__ __launch_bounds__(256, 4)
void orient_conv_kernel(const float* __restrict__ f,
                        const float* __restrict__ r0,
                        const float* __restrict__ r1,
                        const float* __restrict__ tab,
                        float* __restrict__ out)
{
    __shared__ float sIn[3][3][68];    // {f,r0,r1} x 3 rows x cols(-1..64)

    const int tid   = threadIdx.x;
    const int lane  = tid & 63;                              // pixel lane
    const int ocg   = __builtin_amdgcn_readfirstlane(tid >> 6); // wave-uniform
    const int bid   = blockIdx.x;                            // 0..1023
    const int b     = bid >> 8;
    const int rem   = bid & 255;
    const int h     = rem >> 1;
    const int wbase = (rem & 1) << 6;                        // 0 or 64

    v2f acc[4][4];                     // [pair][orient], lanes = {ocA, ocB}
#pragma unroll
    for (int p = 0; p < 4; ++p)
#pragma unroll
        for (int o = 0; o < 4; ++o) acc[p][o] = (v2f)(0.0f);

    for (int c = 0; c < CIN_; ++c) {
        // ---- stage input halo (3 rows x 66 cols) for this c ----
        if (tid < 198) {
            int row = tid / 66;
            int col = tid - row * 66;       // gw = wbase + col - 1
            int gh = h + row - 1;
            int gw = wbase + col - 1;
            bool ok = ((unsigned)gh < (unsigned)H_) & ((unsigned)gw < (unsigned)W_);
            int off = ((b * CIN_ + c) * H_ + gh) * W_ + gw;
            sIn[0][row][col] = ok ? f[off]  : 0.0f;
            sIn[1][row][col] = ok ? r0[off] : 0.0f;
            sIn[2][row][col] = ok ? r1[off] : 0.0f;
        }
        __syncthreads();

        const float* wt = tab + ((size_t)(c * 4 + ocg) * 9) * 48;

#pragma unroll
        for (int tap = 0; tap < 9; ++tap) {
            const int i = tap / 3;
            const int j = tap - i * 3;
            const int col = lane + j;
            float fv  = sIn[0][i][col];
            float r0s = sIn[1][i][col];
            float r1s = sIn[2][i][col];
            v2f fd;  fd[0]  = fv;  fd[1]  = fv;
            v2f r0d; r0d[0] = r0s; r0d[1] = r0s;
            v2f r1d; r1d[0] = r1s; r1d[1] = r1s;
            const float* wp = wt + tap * 48;
#pragma unroll
            for (int p = 0; p < 4; ++p) {
                const v2f* q = reinterpret_cast<const v2f*>(wp + p * 12);
                v2f Cv = q[0], Sv = q[1];
                v2f w0 = q[2], w1 = q[3], w2 = q[4], w3 = q[5];
                v2f u  = __builtin_elementwise_fma(Cv, r0d, Sv * r1d);
                v2f vv = __builtin_elementwise_fma(Cv, r1d, -(Sv * r0d));
                v2f g0 = __builtin_elementwise_max(u,  (v2f)(0.0f));
                v2f g1 = __builtin_elementwise_max(vv, (v2f)(0.0f));
                v2f g2 = g0 - u;     // relu(-u), exact
                v2f g3 = g1 - vv;    // relu(-v), exact
                acc[p][0] = __builtin_elementwise_fma(fd * g0, w0, acc[p][0]);
                acc[p][1] = __builtin_elementwise_fma(fd * g1, w1, acc[p][1]);
                acc[p][2] = __builtin_elementwise_fma(fd * g2, w2, acc[p][2]);
                acc[p][3] = __builtin_elementwise_fma(fd * g3, w3, acc[p][3]);
            }
        }
        __syncthreads();
    }

    // ---- epilogue: max/argmax over orientations (first-max tie-break) ----
    const float cosv[4] = {1.0f, -4.37113883e-08f, -1.0f, 1.19248806e-08f};
    const float sinv[4] = {0.0f, 1.0f, -8.74227766e-08f, -1.0f};
    const int wcol = wbase + lane;
#pragma unroll
    for (int p = 0; p < 4; ++p) {
#pragma unroll
        for (int k = 0; k < 2; ++k) {
            int oc = ocg * 8 + p * 2 + k;
            float a0 = acc[p][0][k], a1 = acc[p][1][k];
            float a2 = acc[p][2][k], a3 = acc[p][3][k];
            float best = a0; int bi = 0;
            if (a1 > best) { best = a1; bi = 1; }
            if (a2 > best) { best = a2; bi = 2; }
            if (a3 > best) { best = a3; bi = 3; }
            size_t o = ((size_t)(b * COUT_ + oc) * H_ + h) * W_ + wcol;
            out[o]              = best;
            out[o + OUTSZ_]     = cosv[bi];
            out[o + 2 * OUTSZ_] = sinv[bi];
        }
    }
}

extern "C" void kernel_launch(void* const* d_in, const int* in_sizes, int n_in,
                              void* d_out, int out_size, void* d_ws, size_t ws_size,
                              hipStream_t stream)
{
    const float* f  = (const float*)d_in[0];
    const float* r0 = (const float*)d_in[1];
    const float* r1 = (const float*)d_in[2];
    const float* w  = (const float*)d_in[3];
    const float* wr = (const float*)d_in[4];
    float* out = (float*)d_out;
    float* tab = (float*)d_ws;    // 221184 B

    build_wtab<<<dim3(36), dim3(256), 0, stream>>>(w, wr, tab);
    orient_conv_kernel<<<dim3(B_ * H_ * 2), dim3(256), 0, stream>>>(
        f, r0, r1, tab, out);
}

// Round 4
// 306.067 us; speedup vs baseline: 1.1812x; 1.0461x over previous
//
#include <hip/hip_runtime.h>

// Orient_Conv: 3x3 orientation-gated conv, 4 orientations + per-pixel argmax.
// B=4, CIN=COUT=32, H=W=128, pad=1.
//
// Gate identity (C=cos(wr), S=sin(wr), r0=cos(th), r1=sin(th)):
//   u = C*r0+S*r1, v = C*r1-S*r0
//   gates: o0=relu(u), o1=relu(v), o2=relu(-u)=relu(u)-u, o3=relu(v)-v
// Rotated weights at tap (i,j): w0=w[i][j], w1=w[2-j][i], w2=w[2-i][2-j],
//   w3=w[j][2-i].
//
// R3 mapping: lane = (oc, pixel-group). Weights are PER-LANE (each lane's own
// oc) loaded from a precomputed global table (coalesced, L1-hot, VMEM pipe) —
// removes the R2 SMEM-serialization and the R1 LDS-weight-pipe wall.
// Pixels pack 2/v2f via column-interleaved LDS [c01][{col,col+32}] so one
// aligned b128 read gives 2 ready v2f pairs (broadcast addresses, 0 movs).
// Block = 512 thr = 32 oc x 16 pxg over (b, h, 64px half-row); thread owns
// 4 px x 1 oc x 4 orients. 1024 blocks x 8 waves = 8192 waves (8/SIMD).

typedef float v2f __attribute__((ext_vector_type(2)));

#define B_    4
#define CIN_  32
#define COUT_ 32
#define H_    128
#define W_    128
#define OUTSZ_ (B_ * COUT_ * H_ * W_)

// tab layout: [cc][tap][oc][8] = {C,S,w0,w1,w2,w3,0,0}; 32*9*32*8 floats = 294912 B
__global__ __launch_bounds__(256)
void build_wtab(const float* __restrict__ w, const float* __restrict__ wr,
                float* __restrict__ tab)
{
    int idx = blockIdx.x * 256 + threadIdx.x;   // ((cc*9+tap)<<5)|oc
    if (idx >= CIN_ * 9 * COUT_) return;        // 9216
    int oc  = idx & 31;
    int t2  = idx >> 5;
    int tap = t2 % 9;
    int cc  = t2 / 9;
    int i = tap / 3, j = tap - i * 3;
    int base = (oc * CIN_ + cc) * 9;
    float w0 = w[base + i * 3 + j];
    float w1 = w[base + (2 - j) * 3 + i];
    float w2 = w[base + (2 - i) * 3 + (2 - j)];
    float w3 = w[base + j * 3 + (2 - i)];
    float S, C;
    sincosf(wr[base + i * 3 + j], &S, &C);
    float* dst = tab + (size_t)idx * 8;
    dst[0] = C;  dst[1] = S;
    dst[2] = w0; dst[3] = w1;
    dst[4] = w2; dst[5] = w3;
    dst[6] = 0.0f; dst[7] = 0.0f;
}

__global__ __launch_bounds__(512, 4)
void orient_conv_kernel(const float* __restrict__ f,
                        const float* __restrict__ r0,
                        const float* __restrict__ r1,
                        const float* __restrict__ tab,
                        float* __restrict__ out)
{
    // interleaved: index = (row*34 + c01)*2 + s ; holds col (c01+32*s) of the
    // 66-col halo window, i.e. gw = wbase + c01 + 32*s - 1
    __shared__ float sF[612], sR0[612], sR1[612];

    const int tid   = threadIdx.x;
    const int oc    = tid & 31;
    const int pxg   = tid >> 5;            // 0..15
    const int p     = pxg << 1;            // even pair index 0..30
    const int bid   = blockIdx.x;          // 0..1023
    const int b     = bid >> 8;
    const int rem   = bid & 255;
    const int h     = rem >> 1;
    const int wbase = (rem & 1) << 6;      // 0 or 64

    // ---- precompute staging descriptors (2 slots/thread per type) ----
    // slot0 = tid (<612 always), slot1 = tid+512 (valid if tid<100)
    int  r_0 = tid / 68, rm0 = tid - r_0 * 68;
    int  c_0 = rm0 >> 1, s_0 = rm0 & 1;
    int  gh0 = h + r_0 - 1, gw0 = wbase + c_0 + (s_0 << 5) - 1;
    bool ok0 = ((unsigned)gh0 < (unsigned)H_) & ((unsigned)gw0 < (unsigned)W_);
    int  go0 = ok0 ? (gh0 * W_ + gw0) : 0;

    int  sl1 = tid + 512;
    bool hv1 = sl1 < 612;
    int  r_1 = sl1 / 68, rm1 = sl1 - r_1 * 68;
    int  c_1 = rm1 >> 1, s_1 = rm1 & 1;
    int  gh1 = h + r_1 - 1, gw1 = wbase + c_1 + (s_1 << 5) - 1;
    bool ok1 = hv1 & ((unsigned)gh1 < (unsigned)H_) & ((unsigned)gw1 < (unsigned)W_);
    int  go1 = ok1 ? (gh1 * W_ + gw1) : 0;

    const int chanBase = b * (CIN_ * H_ * W_);

    v2f acc[2][4];                          // [q][orient]; elems = px, px+32
#pragma unroll
    for (int q = 0; q < 2; ++q)
#pragma unroll
        for (int o = 0; o < 4; ++o) acc[q][o] = (v2f)(0.0f);

    for (int cc = 0; cc < CIN_; ++cc) {
        const int base = chanBase + cc * (H_ * W_);
        sF [tid] = ok0 ? f [base + go0] : 0.0f;
        sR0[tid] = ok0 ? r0[base + go0] : 0.0f;
        sR1[tid] = ok0 ? r1[base + go0] : 0.0f;
        if (hv1) {
            sF [sl1] = ok1 ? f [base + go1] : 0.0f;
            sR0[sl1] = ok1 ? r0[base + go1] : 0.0f;
            sR1[sl1] = ok1 ? r1[base + go1] : 0.0f;
        }
        __syncthreads();

        const float* wcc = tab + (((size_t)cc * 9) << 5) * 8 + oc * 8;

#pragma unroll
        for (int i = 0; i < 3; ++i) {
            // 4 interleaved pixel-pairs [p..p+3] per input, 2 b128 each
            const int wi = i * 68 + (p << 1);
            float4 fA  = *reinterpret_cast<const float4*>(&sF [wi]);
            float4 fB  = *reinterpret_cast<const float4*>(&sF [wi + 4]);
            float4 aA  = *reinterpret_cast<const float4*>(&sR0[wi]);
            float4 aB  = *reinterpret_cast<const float4*>(&sR0[wi + 4]);
            float4 bA  = *reinterpret_cast<const float4*>(&sR1[wi]);
            float4 bB  = *reinterpret_cast<const float4*>(&sR1[wi + 4]);
            v2f fP[4]  = {{fA.x, fA.y}, {fA.z, fA.w}, {fB.x, fB.y}, {fB.z, fB.w}};
            v2f r0P[4] = {{aA.x, aA.y}, {aA.z, aA.w}, {aB.x, aB.y}, {aB.z, aB.w}};
            v2f r1P[4] = {{bA.x, bA.y}, {bA.z, bA.w}, {bB.x, bB.y}, {bB.z, bB.w}};
#pragma unroll
            for (int j = 0; j < 3; ++j) {
                const float* wp = wcc + (i * 3 + j) * 256;   // tap stride 32oc*8
                float4 wA = *reinterpret_cast<const float4*>(wp);      // C,S,w0,w1
                v2f    wB = *reinterpret_cast<const v2f*>(wp + 4);     // w2,w3
                v2f Cd  = {wA.x, wA.x}, Sd  = {wA.y, wA.y};
                v2f w0d = {wA.z, wA.z}, w1d = {wA.w, wA.w};
                v2f w2d = {wB.x, wB.x}, w3d = {wB.y, wB.y};
#pragma unroll
                for (int q = 0; q < 2; ++q) {
                    v2f fv  = fP [q + j];
                    v2f r0v = r0P[q + j];
                    v2f r1v = r1P[q + j];
                    v2f u  = __builtin_elementwise_fma(Cd, r0v, Sd * r1v);
                    v2f vv = __builtin_elementwise_fma(Cd, r1v, -(Sd * r0v));
                    v2f g0 = __builtin_elementwise_max(u,  (v2f)(0.0f));
                    v2f g1 = __builtin_elementwise_max(vv, (v2f)(0.0f));
                    v2f g2 = g0 - u;     // relu(-u), exact
                    v2f g3 = g1 - vv;    // relu(-v), exact
                    acc[q][0] = __builtin_elementwise_fma(fv * g0, w0d, acc[q][0]);
                    acc[q][1] = __builtin_elementwise_fma(fv * g1, w1d, acc[q][1]);
                    acc[q][2] = __builtin_elementwise_fma(fv * g2, w2d, acc[q][2]);
                    acc[q][3] = __builtin_elementwise_fma(fv * g3, w3d, acc[q][3]);
                }
            }
        }
        __syncthreads();
    }

    // ---- epilogue: max/argmax over orientations (first-max tie-break) ----
    const float cosv[4] = {1.0f, -4.37113883e-08f, -1.0f, 1.19248806e-08f};
    const float sinv[4] = {0.0f, 1.0f, -8.74227766e-08f, -1.0f};
#pragma unroll
    for (int q = 0; q < 2; ++q) {
#pragma unroll
        for (int k = 0; k < 2; ++k) {
            int wcol = wbase + p + q + (k << 5);
            float a0 = acc[q][0][k], a1 = acc[q][1][k];
            float a2 = acc[q][2][k], a3 = acc[q][3][k];
            float best = a0; int bi = 0;
            if (a1 > best) { best = a1; bi = 1; }
            if (a2 > best) { best = a2; bi = 2; }
            if (a3 > best) { best = a3; bi = 3; }
            size_t o = ((size_t)(b * COUT_ + oc) * H_ + h) * W_ + wcol;
            out[o]              = best;
            out[o + OUTSZ_]     = cosv[bi];
            out[o + 2 * OUTSZ_] = sinv[bi];
        }
    }
}

extern "C" void kernel_launch(void* const* d_in, const int* in_sizes, int n_in,
                              void* d_out, int out_size, void* d_ws, size_t ws_size,
                              hipStream_t stream)
{
    const float* f  = (const float*)d_in[0];
    const float* r0 = (const float*)d_in[1];
    const float* r1 = (const float*)d_in[2];
    const float* w  = (const float*)d_in[3];
    const float* wr = (const float*)d_in[4];
    float* out = (float*)d_out;
    float* tab = (float*)d_ws;    // 294912 B

    build_wtab<<<dim3(36), dim3(256), 0, stream>>>(w, wr, tab);
    orient_conv_kernel<<<dim3(B_ * H_ * 2), dim3(512), 0, stream>>>(
        f, r0, r1, tab, out);
}